// Round 2
// baseline (670.700 us; speedup 1.0000x reference)
//
#include <hip/hip_runtime.h>
#include <math.h>

#define HEADS 4
#define HD 32
#define DIM 128
#define RPB 16   // rows per block in projection GEMM

// ---------------- K1: h[n,d] = sum_k ent[n,k] * W[d,k]  (entity @ W^T) ----------------
__global__ __launch_bounds__(128) void k_proj(const float* __restrict__ ent,
                                              const float* __restrict__ W,
                                              float* __restrict__ h, int N) {
    __shared__ float4 eT[RPB * 32];  // 16 rows x 128 floats as float4
    int t = threadIdx.x;
    int row0 = blockIdx.x * RPB;
    for (int i = t; i < RPB * 32; i += 128) {
        int r = i >> 5, k4 = i & 31;
        int gr = row0 + r;
        eT[i] = (gr < N) ? ((const float4*)ent)[(size_t)gr * 32 + k4]
                         : make_float4(0.f, 0.f, 0.f, 0.f);
    }
    __syncthreads();
    float acc[RPB];
#pragma unroll
    for (int r = 0; r < RPB; ++r) acc[r] = 0.f;
    const float4* W4 = (const float4*)W;
    int c = t;  // output column (0..127)
#pragma unroll 4
    for (int k4 = 0; k4 < 32; ++k4) {
        float4 w = W4[c * 32 + k4];
#pragma unroll
        for (int r = 0; r < RPB; ++r) {
            float4 e = eT[r * 32 + k4];
            acc[r] += w.x * e.x + w.y * e.y + w.z * e.z + w.w * e.w;
        }
    }
    for (int r = 0; r < RPB; ++r) {
        int gr = row0 + r;
        if (gr < N) h[(size_t)gr * DIM + c] = acc[r];
    }
}

// ---------------- K2: s1[n,h], s3[n,h] partial dots with attn_w ----------------
__global__ __launch_bounds__(256) void k_s13(const float* __restrict__ h,
                                             const float* __restrict__ aw,
                                             float* __restrict__ s1,
                                             float* __restrict__ s3, int N) {
    int i = blockIdx.x * 256 + threadIdx.x;  // i = n*4 + head
    if (i >= N * HEADS) return;
    const float4* h4 = (const float4*)h + (size_t)i * 8;  // n*32 + head*8 float4s
    const float4* aw4 = (const float4*)aw;
    float a1 = 0.f, a3 = 0.f;
#pragma unroll
    for (int j = 0; j < 8; ++j) {
        float4 hv = h4[j];
        float4 w1 = aw4[j];       // aw[0..31]
        float4 w3 = aw4[16 + j];  // aw[64..95]
        a1 += hv.x * w1.x + hv.y * w1.y + hv.z * w1.z + hv.w * w1.w;
        a3 += hv.x * w3.x + hv.y * w3.y + hv.z * w3.z + hv.w * w3.w;
    }
    s1[i] = a1;
    s3[i] = a3;
}

// ---------------- K3: s2[rel,h] ----------------
// Folded: s2[rel,hh] = sum_k rel_emb[rel,k] * v[k,hh],  v[k,hh] = sum_j W_r[hh*32+j,k]*aw[32+j]
__global__ __launch_bounds__(256) void k_s2(const float* __restrict__ rel,
                                            const float* __restrict__ Wr,
                                            const float* __restrict__ aw,
                                            float* __restrict__ s2, int R) {
    __shared__ float v[DIM * HEADS];
    int t = threadIdx.x;
    for (int i = t; i < DIM * HEADS; i += 256) {
        int k = i >> 2, hh = i & 3;
        float acc = 0.f;
        for (int j = 0; j < 32; ++j) acc += Wr[(hh * 32 + j) * DIM + k] * aw[32 + j];
        v[k * 4 + hh] = acc;
    }
    __syncthreads();
    for (int i = t; i < R * HEADS; i += 256) {
        int r = i >> 2, hh = i & 3;
        float acc = 0.f;
        for (int k = 0; k < DIM; ++k) acc += rel[r * DIM + k] * v[k * 4 + hh];
        s2[i] = acc;
    }
}

// ---------------- K4: per-edge scores + global max ----------------
__global__ __launch_bounds__(256) void k_scores(const int* __restrict__ ei,
                                                const int* __restrict__ et,
                                                const float4* __restrict__ s1,
                                                const float4* __restrict__ s2,
                                                const float4* __restrict__ s3,
                                                const float* __restrict__ ab,
                                                float4* __restrict__ scores,
                                                unsigned* __restrict__ gmax, int E) {
    int e = blockIdx.x * 256 + threadIdx.x;
    float m = -1e30f;
    if (e < E) {
        int s = ei[e], dn = ei[E + e], ty = et[e];
        float b = ab[0];
        float4 a = s1[s], c = s2[ty], d = s3[dn];
        float4 sc;
        sc.x = a.x + c.x + d.x + b;
        sc.y = a.y + c.y + d.y + b;
        sc.z = a.z + c.z + d.z + b;
        sc.w = a.w + c.w + d.w + b;
        sc.x = sc.x > 0.f ? sc.x : 0.2f * sc.x;
        sc.y = sc.y > 0.f ? sc.y : 0.2f * sc.y;
        sc.z = sc.z > 0.f ? sc.z : 0.2f * sc.z;
        sc.w = sc.w > 0.f ? sc.w : 0.2f * sc.w;
        scores[e] = sc;
        m = fmaxf(fmaxf(sc.x, sc.y), fmaxf(sc.z, sc.w));
    }
#pragma unroll
    for (int off = 32; off > 0; off >>= 1) m = fmaxf(m, __shfl_down(m, off));
    if ((threadIdx.x & 63) == 0) {
        unsigned u = __float_as_uint(m);
        u = (u & 0x80000000u) ? ~u : (u | 0x80000000u);  // monotone float->uint
        atomicMax(gmax, u);
    }
}

// ---------------- K5: exp(score - gmax), scatter-add attn_sum[dst,h] ----------------
__global__ __launch_bounds__(256) void k_expsum(const int* __restrict__ ei,
                                                float4* __restrict__ scores,
                                                const unsigned* __restrict__ gmax,
                                                float* __restrict__ attn_sum, int E) {
    int e = blockIdx.x * 256 + threadIdx.x;
    if (e >= E) return;
    unsigned u = *gmax;
    u = (u & 0x80000000u) ? (u & 0x7fffffffu) : ~u;  // decode
    float M = __uint_as_float(u);
    float4 sc = scores[e];
    float4 es;
    es.x = __expf(sc.x - M);
    es.y = __expf(sc.y - M);
    es.z = __expf(sc.z - M);
    es.w = __expf(sc.w - M);
    scores[e] = es;
    int dn = ei[E + e];
    unsafeAtomicAdd(&attn_sum[dn * 4 + 0], es.x);
    unsafeAtomicAdd(&attn_sum[dn * 4 + 1], es.y);
    unsafeAtomicAdd(&attn_sum[dn * 4 + 2], es.z);
    unsafeAtomicAdd(&attn_sum[dn * 4 + 3], es.w);
}

// ---------------- K6: out[dst,d] += (es/(sum+1e-8)) * h[src,d] ----------------
__global__ __launch_bounds__(256) void k_scatter(const int* __restrict__ ei,
                                                 const float* __restrict__ scores,
                                                 const float* __restrict__ attn_sum,
                                                 const float* __restrict__ h,
                                                 float* __restrict__ out, int E) {
    long long idx = (long long)blockIdx.x * 256 + threadIdx.x;
    int e = (int)(idx >> 7);
    if (e >= E) return;
    int d = (int)(idx & 127);
    int hh = d >> 5;
    int s = ei[e], dn = ei[E + e];
    float es = scores[e * 4 + hh];
    float asum = attn_sum[dn * 4 + hh];
    float w = es / (asum + 1e-8f);
    float val = w * h[(size_t)s * DIM + d];
    unsafeAtomicAdd(&out[(size_t)dn * DIM + d], val);
}

extern "C" void kernel_launch(void* const* d_in, const int* in_sizes, int n_in,
                              void* d_out, int out_size, void* d_ws, size_t ws_size,
                              hipStream_t stream) {
    const float* ent = (const float*)d_in[0];
    const float* rel = (const float*)d_in[1];
    const int* ei = (const int*)d_in[2];   // [2,E]: src then dst
    const int* et = (const int*)d_in[3];   // [E]
    const float* W = (const float*)d_in[4];
    const float* Wr = (const float*)d_in[5];
    const float* aw = (const float*)d_in[6];
    const float* ab = (const float*)d_in[7];

    int N = in_sizes[0] / DIM;
    int R = in_sizes[1] / DIM;
    int E = in_sizes[3];

    // workspace layout (all 16B-aligned sizes)
    char* w = (char*)d_ws;
    float* h = (float*)w;        w += (size_t)N * DIM * 4;
    float* s1 = (float*)w;       w += (size_t)N * HEADS * 4;
    float* s3 = (float*)w;       w += (size_t)N * HEADS * 4;
    float* s2 = (float*)w;       w += (size_t)R * HEADS * 4;
    float* scores = (float*)w;   w += (size_t)E * HEADS * 4;
    float* attn_sum = (float*)w; w += (size_t)N * HEADS * 4;
    unsigned* gmax = (unsigned*)w;

    float* out = (float*)d_out;

    // zero the accumulators (ws/out are poisoned 0xAA before every call)
    (void)hipMemsetAsync(d_out, 0, (size_t)out_size * 4, stream);
    (void)hipMemsetAsync(attn_sum, 0, (size_t)N * HEADS * 4 + 16, stream);  // includes gmax

    k_proj<<<(N + RPB - 1) / RPB, 128, 0, stream>>>(ent, W, h, N);
    k_s13<<<(N * HEADS + 255) / 256, 256, 0, stream>>>(h, aw, s1, s3, N);
    k_s2<<<1, 256, 0, stream>>>(rel, Wr, aw, s2, R);
    k_scores<<<(E + 255) / 256, 256, 0, stream>>>(ei, et, (const float4*)s1,
                                                  (const float4*)s2, (const float4*)s3,
                                                  ab, (float4*)scores, gmax, E);
    k_expsum<<<(E + 255) / 256, 256, 0, stream>>>(ei, (float4*)scores, gmax, attn_sum, E);
    long long total = (long long)E * DIM;
    k_scatter<<<(unsigned)((total + 255) / 256), 256, 0, stream>>>(ei, scores, attn_sum, h,
                                                                   out, E);
}

// Round 3
// 544.904 us; speedup vs baseline: 1.2309x; 1.2309x over previous
//
#include <hip/hip_runtime.h>
#include <math.h>

#define HEADS 4
#define HD 32
#define DIM 128
#define RPB 16   // rows per block in projection GEMM

// ---------------- K1: h[n,d] = sum_k ent[n,k] * W[d,k]  (entity @ W^T) ----------------
__global__ __launch_bounds__(128) void k_proj(const float* __restrict__ ent,
                                              const float* __restrict__ W,
                                              float* __restrict__ h, int N) {
    __shared__ float4 eT[RPB * 32];  // 16 rows x 128 floats as float4
    int t = threadIdx.x;
    int row0 = blockIdx.x * RPB;
    for (int i = t; i < RPB * 32; i += 128) {
        int r = i >> 5, k4 = i & 31;
        int gr = row0 + r;
        eT[i] = (gr < N) ? ((const float4*)ent)[(size_t)gr * 32 + k4]
                         : make_float4(0.f, 0.f, 0.f, 0.f);
    }
    __syncthreads();
    float acc[RPB];
#pragma unroll
    for (int r = 0; r < RPB; ++r) acc[r] = 0.f;
    const float4* W4 = (const float4*)W;
    int c = t;  // output column (0..127)
#pragma unroll 4
    for (int k4 = 0; k4 < 32; ++k4) {
        float4 w = W4[c * 32 + k4];
#pragma unroll
        for (int r = 0; r < RPB; ++r) {
            float4 e = eT[r * 32 + k4];
            acc[r] += w.x * e.x + w.y * e.y + w.z * e.z + w.w * e.w;
        }
    }
    for (int r = 0; r < RPB; ++r) {
        int gr = row0 + r;
        if (gr < N) h[(size_t)gr * DIM + c] = acc[r];
    }
}

// ---------------- K2: s1[n,h], s3[n,h] partial dots with attn_w ----------------
__global__ __launch_bounds__(256) void k_s13(const float* __restrict__ h,
                                             const float* __restrict__ aw,
                                             float* __restrict__ s1,
                                             float* __restrict__ s3, int N) {
    int i = blockIdx.x * 256 + threadIdx.x;  // i = n*4 + head
    if (i >= N * HEADS) return;
    const float4* h4 = (const float4*)h + (size_t)i * 8;
    const float4* aw4 = (const float4*)aw;
    float a1 = 0.f, a3 = 0.f;
#pragma unroll
    for (int j = 0; j < 8; ++j) {
        float4 hv = h4[j];
        float4 w1 = aw4[j];       // aw[0..31]
        float4 w3 = aw4[16 + j];  // aw[64..95]
        a1 += hv.x * w1.x + hv.y * w1.y + hv.z * w1.z + hv.w * w1.w;
        a3 += hv.x * w3.x + hv.y * w3.y + hv.z * w3.z + hv.w * w3.w;
    }
    s1[i] = a1;
    s3[i] = a3;
}

// ---------------- K3: s2[rel,hh] ----------------
__global__ __launch_bounds__(256) void k_s2(const float* __restrict__ rel,
                                            const float* __restrict__ Wr,
                                            const float* __restrict__ aw,
                                            float* __restrict__ s2, int R) {
    __shared__ float v[DIM * HEADS];
    int t = threadIdx.x;
    for (int i = t; i < DIM * HEADS; i += 256) {
        int k = i >> 2, hh = i & 3;
        float acc = 0.f;
        for (int j = 0; j < 32; ++j) acc += Wr[(hh * 32 + j) * DIM + k] * aw[32 + j];
        v[k * 4 + hh] = acc;
    }
    __syncthreads();
    for (int i = t; i < R * HEADS; i += 256) {
        int r = i >> 2, hh = i & 3;
        float acc = 0.f;
        for (int k = 0; k < DIM; ++k) acc += rel[r * DIM + k] * v[k * 4 + hh];
        s2[i] = acc;
    }
}

// ---------------- K4: global score max + degree count ----------------
__global__ __launch_bounds__(256) void k_scores(const int* __restrict__ ei,
                                                const int* __restrict__ et,
                                                const float4* __restrict__ s1,
                                                const float4* __restrict__ s2,
                                                const float4* __restrict__ s3,
                                                const float* __restrict__ ab,
                                                unsigned* __restrict__ gmax,
                                                int* __restrict__ deg, int E) {
    int e = blockIdx.x * 256 + threadIdx.x;
    float m = -1e30f;
    if (e < E) {
        int s = ei[e], dn = ei[E + e], ty = et[e];
        float b = ab[0];
        float4 a = s1[s], c = s2[ty], d = s3[dn];
        float4 sc;
        sc.x = a.x + c.x + d.x + b;
        sc.y = a.y + c.y + d.y + b;
        sc.z = a.z + c.z + d.z + b;
        sc.w = a.w + c.w + d.w + b;
        sc.x = sc.x > 0.f ? sc.x : 0.2f * sc.x;
        sc.y = sc.y > 0.f ? sc.y : 0.2f * sc.y;
        sc.z = sc.z > 0.f ? sc.z : 0.2f * sc.z;
        sc.w = sc.w > 0.f ? sc.w : 0.2f * sc.w;
        m = fmaxf(fmaxf(sc.x, sc.y), fmaxf(sc.z, sc.w));
        atomicAdd(&deg[dn], 1);
    }
#pragma unroll
    for (int off = 32; off > 0; off >>= 1) m = fmaxf(m, __shfl_down(m, off));
    if ((threadIdx.x & 63) == 0) {
        unsigned u = __float_as_uint(m);
        u = (u & 0x80000000u) ? ~u : (u | 0x80000000u);  // monotone float->uint
        atomicMax(gmax, u);
    }
}

// ---------------- K5: single-block exclusive scan -> CSR offsets ----------------
__global__ __launch_bounds__(1024) void k_scan(const int* __restrict__ deg,
                                               int* __restrict__ offs,
                                               int* __restrict__ cursor, int N) {
    __shared__ int partial[1024];
    int t = threadIdx.x;
    int per = (N + 1023) / 1024;
    int start = t * per;
    int end = start + per;
    if (end > N) end = N;
    int sum = 0;
    for (int i = start; i < end; ++i) sum += deg[i];
    partial[t] = sum;
    __syncthreads();
    for (int off = 1; off < 1024; off <<= 1) {
        int v = (t >= off) ? partial[t - off] : 0;
        __syncthreads();
        partial[t] += v;
        __syncthreads();
    }
    int run = (t > 0) ? partial[t - 1] : 0;
    for (int i = start; i < end; ++i) {
        offs[i] = run;
        cursor[i] = run;
        run += deg[i];
    }
    if (t == 1023) offs[N] = partial[1023];
}

// ---------------- K6: bucket edge ids by dst ----------------
__global__ __launch_bounds__(256) void k_fill(const int* __restrict__ ei,
                                              int* __restrict__ cursor,
                                              int* __restrict__ perm, int E) {
    int e = blockIdx.x * 256 + threadIdx.x;
    if (e >= E) return;
    int dn = ei[E + e];
    int pos = atomicAdd(&cursor[dn], 1);
    perm[pos] = e;
}

// ---------------- K7: gather per destination node ----------------
__global__ __launch_bounds__(128) void k_out(const int* __restrict__ ei,
                                             const int* __restrict__ et,
                                             const int* __restrict__ offs,
                                             const int* __restrict__ perm,
                                             const float* __restrict__ s1,
                                             const float* __restrict__ s2,
                                             const float* __restrict__ s3,
                                             const float* __restrict__ ab,
                                             const unsigned* __restrict__ gmax,
                                             const float* __restrict__ h,
                                             float* __restrict__ out) {
    int n = blockIdx.x;
    int d = threadIdx.x;       // 0..127
    int hh = d >> 5;
    unsigned u = *gmax;
    u = (u & 0x80000000u) ? (u & 0x7fffffffu) : ~u;  // decode
    float M = __uint_as_float(u);
    float b = ab[0];
    float s3n = s3[n * 4 + hh];
    int beg = offs[n], end = offs[n + 1];
    float acc = 0.f, sum = 0.f;
    for (int i = beg; i < end; ++i) {
        int e = perm[i];
        int s = ei[e];
        int ty = et[e];
        float sc = s1[s * 4 + hh] + s2[ty * 4 + hh] + s3n + b;
        sc = sc > 0.f ? sc : 0.2f * sc;
        float es = __expf(sc - M);
        sum += es;
        acc += es * h[(size_t)s * DIM + d];
    }
    out[(size_t)n * DIM + d] = acc / (sum + 1e-8f);
}

extern "C" void kernel_launch(void* const* d_in, const int* in_sizes, int n_in,
                              void* d_out, int out_size, void* d_ws, size_t ws_size,
                              hipStream_t stream) {
    const float* ent = (const float*)d_in[0];
    const float* rel = (const float*)d_in[1];
    const int* ei = (const int*)d_in[2];   // [2,E]: src then dst
    const int* et = (const int*)d_in[3];   // [E]
    const float* W = (const float*)d_in[4];
    const float* Wr = (const float*)d_in[5];
    const float* aw = (const float*)d_in[6];
    const float* ab = (const float*)d_in[7];

    int N = in_sizes[0] / DIM;
    int R = in_sizes[1] / DIM;
    int E = in_sizes[3];

    // workspace layout (16B-aligned chunks)
    char* w = (char*)d_ws;
    float* h = (float*)w;      w += (size_t)N * DIM * 4;
    float* s1 = (float*)w;     w += (size_t)N * HEADS * 4;
    float* s3 = (float*)w;     w += (size_t)N * HEADS * 4;
    float* s2 = (float*)w;     w += ((size_t)R * HEADS * 4 + 15) / 16 * 16;
    int* deg = (int*)w;        w += (size_t)N * 4;
    unsigned* gmax = (unsigned*)w; w += 16;       // memset covers deg+gmax together
    int* offs = (int*)w;       w += (size_t)(N + 1) * 4 + 12;
    int* cursor = (int*)w;     w += (size_t)N * 4;
    int* perm = (int*)w;

    float* out = (float*)d_out;

    // zero deg + gmax (one contiguous memset); out/offs/cursor/perm fully overwritten
    (void)hipMemsetAsync(deg, 0, (size_t)N * 4 + 16, stream);

    k_proj<<<(N + RPB - 1) / RPB, 128, 0, stream>>>(ent, W, h, N);
    k_s13<<<(N * HEADS + 255) / 256, 256, 0, stream>>>(h, aw, s1, s3, N);
    k_s2<<<1, 256, 0, stream>>>(rel, Wr, aw, s2, R);
    k_scores<<<(E + 255) / 256, 256, 0, stream>>>(ei, et, (const float4*)s1,
                                                  (const float4*)s2, (const float4*)s3,
                                                  ab, gmax, deg, E);
    k_scan<<<1, 1024, 0, stream>>>(deg, offs, cursor, N);
    k_fill<<<(E + 255) / 256, 256, 0, stream>>>(ei, cursor, perm, E);
    k_out<<<N, 128, 0, stream>>>(ei, et, offs, perm, s1, s2, s3, ab, gmax, h, out);
}

// Round 4
// 425.427 us; speedup vs baseline: 1.5765x; 1.2808x over previous
//
#include <hip/hip_runtime.h>
#include <math.h>

#define HEADS 4
#define HD 32
#define DIM 128

// ---------------- K1: h = ent @ W^T ; 64x128 tile, 8x4 register blocking ----------------
// thread t: cx = t&31 -> cols {cx, cx+32, cx+64, cx+96}; ry = t>>5 -> rows ry*8..+7
__global__ __launch_bounds__(256) void k_proj(const float* __restrict__ ent,
                                              const float* __restrict__ W,
                                              float* __restrict__ h, int N) {
    __shared__ float4 eT[64 * 32];    // 64 rows x 128 floats (32 KB)
    __shared__ float4 wT[128 * 9];    // 128 cols x 8 float4 (+1 pad) (18.4 KB)
    int t = threadIdx.x;
    int row0 = blockIdx.x * 64;
    const float4* ent4 = (const float4*)ent;
    const float4* W4 = (const float4*)W;
    for (int i = t; i < 64 * 32; i += 256) {
        int r = row0 + (i >> 5);
        eT[i] = (r < N) ? ent4[(size_t)r * 32 + (i & 31)] : make_float4(0.f, 0.f, 0.f, 0.f);
    }
    int cx = t & 31;
    int ry = t >> 5;
    float acc[8][4] = {};
    for (int kc = 0; kc < 4; ++kc) {
        __syncthreads();  // also covers eT staging at kc=0
        for (int i = t; i < 128 * 8; i += 256) {
            int col = i >> 3, j = i & 7;
            wT[col * 9 + j] = W4[col * 32 + kc * 8 + j];
        }
        __syncthreads();
#pragma unroll
        for (int j = 0; j < 8; ++j) {
            float4 a[8], b[4];
#pragma unroll
            for (int r = 0; r < 8; ++r) a[r] = eT[(ry * 8 + r) * 32 + kc * 8 + j];
#pragma unroll
            for (int c = 0; c < 4; ++c) b[c] = wT[(cx + 32 * c) * 9 + j];
#pragma unroll
            for (int r = 0; r < 8; ++r)
#pragma unroll
                for (int c = 0; c < 4; ++c)
                    acc[r][c] += a[r].x * b[c].x + a[r].y * b[c].y +
                                 a[r].z * b[c].z + a[r].w * b[c].w;
        }
    }
    for (int r = 0; r < 8; ++r) {
        int gr = row0 + ry * 8 + r;
        if (gr < N) {
#pragma unroll
            for (int c = 0; c < 4; ++c)
                h[(size_t)gr * DIM + cx + 32 * c] = acc[r][c];
        }
    }
}

// ---------------- K2: s1[n,h], s3[n,h] ----------------
__global__ __launch_bounds__(256) void k_s13(const float* __restrict__ h,
                                             const float* __restrict__ aw,
                                             float* __restrict__ s1,
                                             float* __restrict__ s3, int N) {
    int i = blockIdx.x * 256 + threadIdx.x;  // i = n*4 + head
    if (i >= N * HEADS) return;
    const float4* h4 = (const float4*)h + (size_t)i * 8;
    const float4* aw4 = (const float4*)aw;
    float a1 = 0.f, a3 = 0.f;
#pragma unroll
    for (int j = 0; j < 8; ++j) {
        float4 hv = h4[j];
        float4 w1 = aw4[j];
        float4 w3 = aw4[16 + j];
        a1 += hv.x * w1.x + hv.y * w1.y + hv.z * w1.z + hv.w * w1.w;
        a3 += hv.x * w3.x + hv.y * w3.y + hv.z * w3.z + hv.w * w3.w;
    }
    s1[i] = a1;
    s3[i] = a3;
}

// ---------------- K3a: v[k,hh] = sum_j W_r[hh*32+j,k]*aw[32+j] ----------------
__global__ __launch_bounds__(256) void k_v(const float* __restrict__ Wr,
                                           const float* __restrict__ aw,
                                           float* __restrict__ v) {
    int i = blockIdx.x * 256 + threadIdx.x;
    if (i >= DIM * HEADS) return;
    int k = i >> 2, hh = i & 3;
    float acc = 0.f;
    for (int j = 0; j < 32; ++j) acc += Wr[(hh * 32 + j) * DIM + k] * aw[32 + j];
    v[k * 4 + hh] = acc;
}

// ---------------- K3b: s2[rel,hh] = rel_emb[rel,:] . v[:,hh] — one wave per output ----------------
__global__ __launch_bounds__(256) void k_s2(const float* __restrict__ rel,
                                            const float* __restrict__ v,
                                            float* __restrict__ s2, int RH) {
    int t = threadIdx.x;
    int o = blockIdx.x * 4 + (t >> 6);
    if (o >= RH) return;
    int r = o >> 2, hh = o & 3;
    int l = t & 63;
    float p = rel[r * DIM + l] * v[l * 4 + hh] + rel[r * DIM + 64 + l] * v[(64 + l) * 4 + hh];
#pragma unroll
    for (int off = 32; off > 0; off >>= 1) p += __shfl_down(p, off);
    if (l == 0) s2[o] = p;
}

// ---------------- K4: global score max + degree count ----------------
__global__ __launch_bounds__(256) void k_scores(const int* __restrict__ ei,
                                                const int* __restrict__ et,
                                                const float4* __restrict__ s1,
                                                const float4* __restrict__ s2,
                                                const float4* __restrict__ s3,
                                                const float* __restrict__ ab,
                                                unsigned* __restrict__ gmax,
                                                int* __restrict__ deg, int E) {
    int e = blockIdx.x * 256 + threadIdx.x;
    float m = -1e30f;
    if (e < E) {
        int s = ei[e], dn = ei[E + e], ty = et[e];
        float b = ab[0];
        float4 a = s1[s], c = s2[ty], d = s3[dn];
        float4 sc;
        sc.x = a.x + c.x + d.x + b;
        sc.y = a.y + c.y + d.y + b;
        sc.z = a.z + c.z + d.z + b;
        sc.w = a.w + c.w + d.w + b;
        sc.x = sc.x > 0.f ? sc.x : 0.2f * sc.x;
        sc.y = sc.y > 0.f ? sc.y : 0.2f * sc.y;
        sc.z = sc.z > 0.f ? sc.z : 0.2f * sc.z;
        sc.w = sc.w > 0.f ? sc.w : 0.2f * sc.w;
        m = fmaxf(fmaxf(sc.x, sc.y), fmaxf(sc.z, sc.w));
        atomicAdd(&deg[dn], 1);
    }
#pragma unroll
    for (int off = 32; off > 0; off >>= 1) m = fmaxf(m, __shfl_down(m, off));
    if ((threadIdx.x & 63) == 0) {
        unsigned u = __float_as_uint(m);
        u = (u & 0x80000000u) ? ~u : (u | 0x80000000u);  // monotone float->uint
        atomicMax(gmax, u);
    }
}

// ---------------- K5: single-block exclusive scan -> CSR offsets ----------------
__global__ __launch_bounds__(1024) void k_scan(const int* __restrict__ deg,
                                               int* __restrict__ offs,
                                               int* __restrict__ cursor, int N) {
    __shared__ int partial[1024];
    int t = threadIdx.x;
    int per = (N + 1023) / 1024;
    int start = t * per;
    int end = start + per;
    if (end > N) end = N;
    int sum = 0;
    for (int i = start; i < end; ++i) sum += deg[i];
    partial[t] = sum;
    __syncthreads();
    for (int off = 1; off < 1024; off <<= 1) {
        int v = (t >= off) ? partial[t - off] : 0;
        __syncthreads();
        partial[t] += v;
        __syncthreads();
    }
    int run = (t > 0) ? partial[t - 1] : 0;
    for (int i = start; i < end; ++i) {
        offs[i] = run;
        cursor[i] = run;
        run += deg[i];
    }
    if (t == 1023) offs[N] = partial[1023];
}

// ---------------- K6: bucket packed (src<<6)|ty by dst ----------------
__global__ __launch_bounds__(256) void k_fill(const int* __restrict__ ei,
                                              const int* __restrict__ et,
                                              int* __restrict__ cursor,
                                              int* __restrict__ packed, int E) {
    int e = blockIdx.x * 256 + threadIdx.x;
    if (e >= E) return;
    int dn = ei[E + e];
    int p = (ei[e] << 6) | et[e];
    int pos = atomicAdd(&cursor[dn], 1);
    packed[pos] = p;
}

// ---------------- K7: gather per destination node, chunked via LDS ----------------
__global__ __launch_bounds__(128) void k_out(const int* __restrict__ packed,
                                             const int* __restrict__ offs,
                                             const float4* __restrict__ s1,
                                             const float4* __restrict__ s2,
                                             const float4* __restrict__ s3,
                                             const float* __restrict__ ab,
                                             const unsigned* __restrict__ gmax,
                                             const float* __restrict__ h,
                                             float* __restrict__ out) {
    __shared__ int src_l[128];
    __shared__ float es_l[128 * 4];
    int n = blockIdx.x;
    int d = threadIdx.x;  // 0..127
    int t = d;
    int hh = d >> 5;
    unsigned u = *gmax;
    u = (u & 0x80000000u) ? (u & 0x7fffffffu) : ~u;  // decode
    float M = __uint_as_float(u);
    float b = ab[0];
    float4 s3n = s3[n];
    int beg = offs[n], end = offs[n + 1];
    int cnt = end - beg;
    float acc = 0.f, sum = 0.f;
    for (int base = 0; base < cnt; base += 128) {
        int m = cnt - base;
        if (m > 128) m = 128;
        __syncthreads();
        if (t < m) {
            int p = packed[beg + base + t];
            int s = p >> 6, ty = p & 63;
            float4 a = s1[s], c = s2[ty];
            float4 sc;
            sc.x = a.x + c.x + s3n.x + b;
            sc.y = a.y + c.y + s3n.y + b;
            sc.z = a.z + c.z + s3n.z + b;
            sc.w = a.w + c.w + s3n.w + b;
            sc.x = sc.x > 0.f ? sc.x : 0.2f * sc.x;
            sc.y = sc.y > 0.f ? sc.y : 0.2f * sc.y;
            sc.z = sc.z > 0.f ? sc.z : 0.2f * sc.z;
            sc.w = sc.w > 0.f ? sc.w : 0.2f * sc.w;
            src_l[t] = s;
            es_l[t * 4 + 0] = __expf(sc.x - M);
            es_l[t * 4 + 1] = __expf(sc.y - M);
            es_l[t * 4 + 2] = __expf(sc.z - M);
            es_l[t * 4 + 3] = __expf(sc.w - M);
        }
        __syncthreads();
        int i = 0;
        for (; i + 4 <= m; i += 4) {
            int a0 = src_l[i], a1 = src_l[i + 1], a2 = src_l[i + 2], a3 = src_l[i + 3];
            float e0 = es_l[i * 4 + hh], e1 = es_l[(i + 1) * 4 + hh];
            float e2 = es_l[(i + 2) * 4 + hh], e3 = es_l[(i + 3) * 4 + hh];
            float f0 = h[(size_t)a0 * DIM + d];
            float f1 = h[(size_t)a1 * DIM + d];
            float f2 = h[(size_t)a2 * DIM + d];
            float f3 = h[(size_t)a3 * DIM + d];
            sum += (e0 + e1) + (e2 + e3);
            acc += e0 * f0;
            acc += e1 * f1;
            acc += e2 * f2;
            acc += e3 * f3;
        }
        for (; i < m; ++i) {
            int s = src_l[i];
            float e = es_l[i * 4 + hh];
            sum += e;
            acc += e * h[(size_t)s * DIM + d];
        }
    }
    out[(size_t)n * DIM + d] = acc / (sum + 1e-8f);
}

extern "C" void kernel_launch(void* const* d_in, const int* in_sizes, int n_in,
                              void* d_out, int out_size, void* d_ws, size_t ws_size,
                              hipStream_t stream) {
    const float* ent = (const float*)d_in[0];
    const float* rel = (const float*)d_in[1];
    const int* ei = (const int*)d_in[2];   // [2,E]: src then dst
    const int* et = (const int*)d_in[3];   // [E]
    const float* W = (const float*)d_in[4];
    const float* Wr = (const float*)d_in[5];
    const float* aw = (const float*)d_in[6];
    const float* ab = (const float*)d_in[7];

    int N = in_sizes[0] / DIM;
    int R = in_sizes[1] / DIM;
    int E = in_sizes[3];

    // workspace layout (16B-aligned chunks)
    char* w = (char*)d_ws;
    float* h = (float*)w;      w += (size_t)N * DIM * 4;
    float* s1 = (float*)w;     w += (size_t)N * HEADS * 4;
    float* s3 = (float*)w;     w += (size_t)N * HEADS * 4;
    float* s2 = (float*)w;     w += ((size_t)R * HEADS * 4 + 15) / 16 * 16;
    float* v = (float*)w;      w += (size_t)DIM * HEADS * 4;
    int* deg = (int*)w;        w += (size_t)N * 4;
    unsigned* gmax = (unsigned*)w; w += 16;  // memset covers deg+gmax together
    int* offs = (int*)w;       w += ((size_t)(N + 1) * 4 + 15) / 16 * 16;
    int* cursor = (int*)w;     w += (size_t)N * 4;
    int* packed = (int*)w;

    float* out = (float*)d_out;

    (void)hipMemsetAsync(deg, 0, (size_t)N * 4 + 16, stream);

    k_proj<<<(N + 63) / 64, 256, 0, stream>>>(ent, W, h, N);
    k_s13<<<(N * HEADS + 255) / 256, 256, 0, stream>>>(h, aw, s1, s3, N);
    k_v<<<(DIM * HEADS + 255) / 256, 256, 0, stream>>>(Wr, aw, v);
    k_s2<<<(R * HEADS + 3) / 4, 256, 0, stream>>>(rel, v, s2, R * HEADS);
    k_scores<<<(E + 255) / 256, 256, 0, stream>>>(ei, et, (const float4*)s1,
                                                  (const float4*)s2, (const float4*)s3,
                                                  ab, gmax, deg, E);
    k_scan<<<1, 1024, 0, stream>>>(deg, offs, cursor, N);
    k_fill<<<(E + 255) / 256, 256, 0, stream>>>(ei, et, cursor, packed, E);
    k_out<<<N, 128, 0, stream>>>(packed, offs, (const float4*)s1, (const float4*)s2,
                                 (const float4*)s3, ab, gmax, h, out);
}

// Round 5
// 328.034 us; speedup vs baseline: 2.0446x; 1.2969x over previous
//
#include <hip/hip_runtime.h>
#include <math.h>

#define HEADS 4
#define HD 32
#define DIM 128

// ---------------- K1: h = ent @ W^T ; 64x128 tile, 8x4 register blocking ----------------
__global__ __launch_bounds__(256) void k_proj(const float* __restrict__ ent,
                                              const float* __restrict__ W,
                                              float* __restrict__ h, int N) {
    __shared__ float4 eT[64 * 32];    // 64 rows x 128 floats (32 KB)
    __shared__ float4 wT[128 * 9];    // 128 cols x 8 float4 (+1 pad)
    int t = threadIdx.x;
    int row0 = blockIdx.x * 64;
    const float4* ent4 = (const float4*)ent;
    const float4* W4 = (const float4*)W;
    for (int i = t; i < 64 * 32; i += 256) {
        int r = row0 + (i >> 5);
        eT[i] = (r < N) ? ent4[(size_t)r * 32 + (i & 31)] : make_float4(0.f, 0.f, 0.f, 0.f);
    }
    int cx = t & 31;
    int ry = t >> 5;
    float acc[8][4] = {};
    for (int kc = 0; kc < 4; ++kc) {
        __syncthreads();  // also covers eT staging at kc=0
        for (int i = t; i < 128 * 8; i += 256) {
            int col = i >> 3, j = i & 7;
            wT[col * 9 + j] = W4[col * 32 + kc * 8 + j];
        }
        __syncthreads();
#pragma unroll
        for (int j = 0; j < 8; ++j) {
            float4 a[8], b[4];
#pragma unroll
            for (int r = 0; r < 8; ++r) a[r] = eT[(ry * 8 + r) * 32 + kc * 8 + j];
#pragma unroll
            for (int c = 0; c < 4; ++c) b[c] = wT[(cx + 32 * c) * 9 + j];
#pragma unroll
            for (int r = 0; r < 8; ++r)
#pragma unroll
                for (int c = 0; c < 4; ++c)
                    acc[r][c] += a[r].x * b[c].x + a[r].y * b[c].y +
                                 a[r].z * b[c].z + a[r].w * b[c].w;
        }
    }
    for (int r = 0; r < 8; ++r) {
        int gr = row0 + ry * 8 + r;
        if (gr < N) {
#pragma unroll
            for (int c = 0; c < 4; ++c)
                h[(size_t)gr * DIM + cx + 32 * c] = acc[r][c];
        }
    }
}

// ---------------- K2: s1[n,h], s3[n,h] ----------------
__global__ __launch_bounds__(256) void k_s13(const float* __restrict__ h,
                                             const float* __restrict__ aw,
                                             float* __restrict__ s1,
                                             float* __restrict__ s3, int N) {
    int i = blockIdx.x * 256 + threadIdx.x;  // i = n*4 + head
    if (i >= N * HEADS) return;
    const float4* h4 = (const float4*)h + (size_t)i * 8;
    const float4* aw4 = (const float4*)aw;
    float a1 = 0.f, a3 = 0.f;
#pragma unroll
    for (int j = 0; j < 8; ++j) {
        float4 hv = h4[j];
        float4 w1 = aw4[j];
        float4 w3 = aw4[16 + j];
        a1 += hv.x * w1.x + hv.y * w1.y + hv.z * w1.z + hv.w * w1.w;
        a3 += hv.x * w3.x + hv.y * w3.y + hv.z * w3.z + hv.w * w3.w;
    }
    s1[i] = a1;
    s3[i] = a3;
}

// ---------------- K3a: v[k,hh] = sum_j W_r[hh*32+j,k]*aw[32+j] ----------------
__global__ __launch_bounds__(256) void k_v(const float* __restrict__ Wr,
                                           const float* __restrict__ aw,
                                           float* __restrict__ v) {
    int i = blockIdx.x * 256 + threadIdx.x;
    if (i >= DIM * HEADS) return;
    int k = i >> 2, hh = i & 3;
    float acc = 0.f;
    for (int j = 0; j < 32; ++j) acc += Wr[(hh * 32 + j) * DIM + k] * aw[32 + j];
    v[k * 4 + hh] = acc;
}

// ---------------- K3b: s2[rel,hh] — one wave per output ----------------
__global__ __launch_bounds__(256) void k_s2(const float* __restrict__ rel,
                                            const float* __restrict__ v,
                                            float* __restrict__ s2, int RH) {
    int t = threadIdx.x;
    int o = blockIdx.x * 4 + (t >> 6);
    if (o >= RH) return;
    int r = o >> 2, hh = o & 3;
    int l = t & 63;
    float p = rel[r * DIM + l] * v[l * 4 + hh] + rel[r * DIM + 64 + l] * v[(64 + l) * 4 + hh];
#pragma unroll
    for (int off = 32; off > 0; off >>= 1) p += __shfl_down(p, off);
    if (l == 0) s2[o] = p;
}

// ---------------- K4: degree count only (global max eliminated — scores bounded,
// exp(s) safe in fp32; 1e-8 denominator effect < 1e-5 abs, threshold is 5.8e-2) --------
__global__ __launch_bounds__(256) void k_deg(const int* __restrict__ ei,
                                             int* __restrict__ deg, int E) {
    int e = blockIdx.x * 256 + threadIdx.x;
    if (e >= E) return;
    atomicAdd(&deg[ei[E + e]], 1);
}

// ---------------- K5: single-block exclusive scan -> CSR offsets ----------------
__global__ __launch_bounds__(1024) void k_scan(const int* __restrict__ deg,
                                               int* __restrict__ offs,
                                               int* __restrict__ cursor, int N) {
    __shared__ int partial[1024];
    int t = threadIdx.x;
    int per = (N + 1023) / 1024;
    int start = t * per;
    int end = start + per;
    if (end > N) end = N;
    int sum = 0;
    for (int i = start; i < end; ++i) sum += deg[i];
    partial[t] = sum;
    __syncthreads();
    for (int off = 1; off < 1024; off <<= 1) {
        int v = (t >= off) ? partial[t - off] : 0;
        __syncthreads();
        partial[t] += v;
        __syncthreads();
    }
    int run = (t > 0) ? partial[t - 1] : 0;
    for (int i = start; i < end; ++i) {
        offs[i] = run;
        cursor[i] = run;
        run += deg[i];
    }
    if (t == 1023) offs[N] = partial[1023];
}

// ---------------- K6: bucket packed (src<<6)|ty by dst ----------------
__global__ __launch_bounds__(256) void k_fill(const int* __restrict__ ei,
                                              const int* __restrict__ et,
                                              int* __restrict__ cursor,
                                              int* __restrict__ packed, int E) {
    int e = blockIdx.x * 256 + threadIdx.x;
    if (e >= E) return;
    int dn = ei[E + e];
    int p = (ei[e] << 6) | et[e];
    int pos = atomicAdd(&cursor[dn], 1);
    packed[pos] = p;
}

// ---------------- K7: gather per destination node, chunked via LDS ----------------
__global__ __launch_bounds__(128) void k_out(const int* __restrict__ packed,
                                             const int* __restrict__ offs,
                                             const float4* __restrict__ s1,
                                             const float4* __restrict__ s2,
                                             const float4* __restrict__ s3,
                                             const float* __restrict__ ab,
                                             const float* __restrict__ h,
                                             float* __restrict__ out) {
    __shared__ int src_l[128];
    __shared__ float es_l[128 * 4];
    int n = blockIdx.x;
    int d = threadIdx.x;  // 0..127
    int t = d;
    int hh = d >> 5;
    float b = ab[0];
    float4 s3n = s3[n];
    int beg = offs[n], end = offs[n + 1];
    int cnt = end - beg;
    float acc = 0.f, sum = 0.f;
    for (int base = 0; base < cnt; base += 128) {
        int m = cnt - base;
        if (m > 128) m = 128;
        __syncthreads();
        if (t < m) {
            int p = packed[beg + base + t];
            int s = p >> 6, ty = p & 63;
            float4 a = s1[s], c = s2[ty];
            float4 sc;
            sc.x = a.x + c.x + s3n.x + b;
            sc.y = a.y + c.y + s3n.y + b;
            sc.z = a.z + c.z + s3n.z + b;
            sc.w = a.w + c.w + s3n.w + b;
            sc.x = sc.x > 0.f ? sc.x : 0.2f * sc.x;
            sc.y = sc.y > 0.f ? sc.y : 0.2f * sc.y;
            sc.z = sc.z > 0.f ? sc.z : 0.2f * sc.z;
            sc.w = sc.w > 0.f ? sc.w : 0.2f * sc.w;
            src_l[t] = s;
            es_l[t * 4 + 0] = __expf(sc.x);
            es_l[t * 4 + 1] = __expf(sc.y);
            es_l[t * 4 + 2] = __expf(sc.z);
            es_l[t * 4 + 3] = __expf(sc.w);
        }
        __syncthreads();
        int i = 0;
        for (; i + 4 <= m; i += 4) {
            int a0 = src_l[i], a1 = src_l[i + 1], a2 = src_l[i + 2], a3 = src_l[i + 3];
            float e0 = es_l[i * 4 + hh], e1 = es_l[(i + 1) * 4 + hh];
            float e2 = es_l[(i + 2) * 4 + hh], e3 = es_l[(i + 3) * 4 + hh];
            float f0 = h[(size_t)a0 * DIM + d];
            float f1 = h[(size_t)a1 * DIM + d];
            float f2 = h[(size_t)a2 * DIM + d];
            float f3 = h[(size_t)a3 * DIM + d];
            sum += (e0 + e1) + (e2 + e3);
            acc += e0 * f0;
            acc += e1 * f1;
            acc += e2 * f2;
            acc += e3 * f3;
        }
        for (; i < m; ++i) {
            int s = src_l[i];
            float e = es_l[i * 4 + hh];
            sum += e;
            acc += e * h[(size_t)s * DIM + d];
        }
    }
    out[(size_t)n * DIM + d] = acc / (sum + 1e-8f);
}

extern "C" void kernel_launch(void* const* d_in, const int* in_sizes, int n_in,
                              void* d_out, int out_size, void* d_ws, size_t ws_size,
                              hipStream_t stream) {
    const float* ent = (const float*)d_in[0];
    const float* rel = (const float*)d_in[1];
    const int* ei = (const int*)d_in[2];   // [2,E]: src then dst
    const int* et = (const int*)d_in[3];   // [E]
    const float* W = (const float*)d_in[4];
    const float* Wr = (const float*)d_in[5];
    const float* aw = (const float*)d_in[6];
    const float* ab = (const float*)d_in[7];

    int N = in_sizes[0] / DIM;
    int R = in_sizes[1] / DIM;
    int E = in_sizes[3];

    // workspace layout (16B-aligned chunks)
    char* w = (char*)d_ws;
    float* h = (float*)w;      w += (size_t)N * DIM * 4;
    float* s1 = (float*)w;     w += (size_t)N * HEADS * 4;
    float* s3 = (float*)w;     w += (size_t)N * HEADS * 4;
    float* s2 = (float*)w;     w += ((size_t)R * HEADS * 4 + 15) / 16 * 16;
    float* v = (float*)w;      w += (size_t)DIM * HEADS * 4;
    int* deg = (int*)w;        w += (size_t)N * 4 + 16;
    int* offs = (int*)w;       w += ((size_t)(N + 1) * 4 + 15) / 16 * 16;
    int* cursor = (int*)w;     w += (size_t)N * 4;
    int* packed = (int*)w;

    float* out = (float*)d_out;

    (void)hipMemsetAsync(deg, 0, (size_t)N * 4, stream);

    k_proj<<<(N + 63) / 64, 256, 0, stream>>>(ent, W, h, N);
    k_s13<<<(N * HEADS + 255) / 256, 256, 0, stream>>>(h, aw, s1, s3, N);
    k_v<<<(DIM * HEADS + 255) / 256, 256, 0, stream>>>(Wr, aw, v);
    k_s2<<<(R * HEADS + 3) / 4, 256, 0, stream>>>(rel, v, s2, R * HEADS);
    k_deg<<<(E + 255) / 256, 256, 0, stream>>>(ei, deg, E);
    k_scan<<<1, 1024, 0, stream>>>(deg, offs, cursor, N);
    k_fill<<<(E + 255) / 256, 256, 0, stream>>>(ei, et, cursor, packed, E);
    k_out<<<N, 128, 0, stream>>>(packed, offs, (const float4*)s1, (const float4*)s2,
                                 (const float4*)s3, ab, h, out);
}

// Round 6
// 247.873 us; speedup vs baseline: 2.7058x; 1.3234x over previous
//
#include <hip/hip_runtime.h>
#include <math.h>

#define HEADS 4
#define HD 32
#define DIM 128

// ---------------- K1: h = ent @ W^T ; 64x128 tile, 8x4 register blocking ----------------
__global__ __launch_bounds__(256) void k_proj(const float* __restrict__ ent,
                                              const float* __restrict__ W,
                                              float* __restrict__ h, int N) {
    __shared__ float4 eT[64 * 32];    // 64 rows x 128 floats (32 KB)
    __shared__ float4 wT[128 * 9];    // 128 cols x 8 float4 (+1 pad)
    int t = threadIdx.x;
    int row0 = blockIdx.x * 64;
    const float4* ent4 = (const float4*)ent;
    const float4* W4 = (const float4*)W;
    for (int i = t; i < 64 * 32; i += 256) {
        int r = row0 + (i >> 5);
        eT[i] = (r < N) ? ent4[(size_t)r * 32 + (i & 31)] : make_float4(0.f, 0.f, 0.f, 0.f);
    }
    int cx = t & 31;
    int ry = t >> 5;
    float acc[8][4] = {};
    for (int kc = 0; kc < 4; ++kc) {
        __syncthreads();  // also covers eT staging at kc=0
        for (int i = t; i < 128 * 8; i += 256) {
            int col = i >> 3, j = i & 7;
            wT[col * 9 + j] = W4[col * 32 + kc * 8 + j];
        }
        __syncthreads();
#pragma unroll
        for (int j = 0; j < 8; ++j) {
            float4 a[8], b[4];
#pragma unroll
            for (int r = 0; r < 8; ++r) a[r] = eT[(ry * 8 + r) * 32 + kc * 8 + j];
#pragma unroll
            for (int c = 0; c < 4; ++c) b[c] = wT[(cx + 32 * c) * 9 + j];
#pragma unroll
            for (int r = 0; r < 8; ++r)
#pragma unroll
                for (int c = 0; c < 4; ++c)
                    acc[r][c] += a[r].x * b[c].x + a[r].y * b[c].y +
                                 a[r].z * b[c].z + a[r].w * b[c].w;
        }
    }
    for (int r = 0; r < 8; ++r) {
        int gr = row0 + ry * 8 + r;
        if (gr < N) {
#pragma unroll
            for (int c = 0; c < 4; ++c)
                h[(size_t)gr * DIM + cx + 32 * c] = acc[r][c];
        }
    }
}

// ---------------- K2: s1[n,h], s3[n,h] ----------------
__global__ __launch_bounds__(256) void k_s13(const float* __restrict__ h,
                                             const float* __restrict__ aw,
                                             float* __restrict__ s1,
                                             float* __restrict__ s3, int N) {
    int i = blockIdx.x * 256 + threadIdx.x;  // i = n*4 + head
    if (i >= N * HEADS) return;
    const float4* h4 = (const float4*)h + (size_t)i * 8;
    const float4* aw4 = (const float4*)aw;
    float a1 = 0.f, a3 = 0.f;
#pragma unroll
    for (int j = 0; j < 8; ++j) {
        float4 hv = h4[j];
        float4 w1 = aw4[j];
        float4 w3 = aw4[16 + j];
        a1 += hv.x * w1.x + hv.y * w1.y + hv.z * w1.z + hv.w * w1.w;
        a3 += hv.x * w3.x + hv.y * w3.y + hv.z * w3.z + hv.w * w3.w;
    }
    s1[i] = a1;
    s3[i] = a3;
}

// ---------------- K3a: v[k,hh] = sum_j W_r[hh*32+j,k]*aw[32+j] ----------------
__global__ __launch_bounds__(256) void k_v(const float* __restrict__ Wr,
                                           const float* __restrict__ aw,
                                           float* __restrict__ v) {
    int i = blockIdx.x * 256 + threadIdx.x;
    if (i >= DIM * HEADS) return;
    int k = i >> 2, hh = i & 3;
    float acc = 0.f;
    for (int j = 0; j < 32; ++j) acc += Wr[(hh * 32 + j) * DIM + k] * aw[32 + j];
    v[k * 4 + hh] = acc;
}

// ---------------- K3b: s2[rel,hh] — one wave per output ----------------
__global__ __launch_bounds__(256) void k_s2(const float* __restrict__ rel,
                                            const float* __restrict__ v,
                                            float* __restrict__ s2, int RH) {
    int t = threadIdx.x;
    int o = blockIdx.x * 4 + (t >> 6);
    if (o >= RH) return;
    int r = o >> 2, hh = o & 3;
    int l = t & 63;
    float p = rel[r * DIM + l] * v[l * 4 + hh] + rel[r * DIM + 64 + l] * v[(64 + l) * 4 + hh];
#pragma unroll
    for (int off = 32; off > 0; off >>= 1) p += __shfl_down(p, off);
    if (l == 0) s2[o] = p;
}

// ---------------- K4: degree count ----------------
__global__ __launch_bounds__(256) void k_deg(const int* __restrict__ ei,
                                             int* __restrict__ deg, int E) {
    int e = blockIdx.x * 256 + threadIdx.x;
    if (e >= E) return;
    atomicAdd(&deg[ei[E + e]], 1);
}

// ---------------- K5a: per-block scan of deg; local exclusive -> offs, total -> bsum ----
__global__ __launch_bounds__(256) void k_scanA(const int* __restrict__ deg,
                                               int* __restrict__ offs,
                                               int* __restrict__ bsum, int N) {
    __shared__ int sm[256];
    int t = threadIdx.x;
    int i = blockIdx.x * 256 + t;
    int v = (i < N) ? deg[i] : 0;
    sm[t] = v;
    __syncthreads();
    for (int off = 1; off < 256; off <<= 1) {
        int x = (t >= off) ? sm[t - off] : 0;
        __syncthreads();
        sm[t] += x;
        __syncthreads();
    }
    if (i < N) offs[i] = sm[t] - v;  // block-local exclusive
    if (t == 255) bsum[blockIdx.x] = sm[255];
}

// ---------------- K5b: exclusive scan of bsum in place (nb ~ 157), total -> offs[N] ----
__global__ __launch_bounds__(1024) void k_scanB(int* __restrict__ bsum,
                                                int* __restrict__ offs,
                                                int N, int nb) {
    __shared__ int partial[1024];
    int t = threadIdx.x;
    int per = (nb + 1023) / 1024;
    int start = t * per;
    int end = start + per;
    if (end > nb) end = nb;
    int sum = 0;
    for (int i = start; i < end; ++i) sum += bsum[i];
    partial[t] = sum;
    __syncthreads();
    for (int off = 1; off < 1024; off <<= 1) {
        int x = (t >= off) ? partial[t - off] : 0;
        __syncthreads();
        partial[t] += x;
        __syncthreads();
    }
    int run = (t > 0) ? partial[t - 1] : 0;
    for (int i = start; i < end; ++i) {
        int v = bsum[i];
        bsum[i] = run;
        run += v;
    }
    if (t == 1023) offs[N] = partial[1023];
}

// ---------------- K5c: add block prefix; mirror into cursor ----------------
__global__ __launch_bounds__(256) void k_scanC(const int* __restrict__ bsum,
                                               int* __restrict__ offs,
                                               int* __restrict__ cursor, int N) {
    int i = blockIdx.x * 256 + threadIdx.x;
    if (i >= N) return;
    int o = offs[i] + bsum[blockIdx.x];
    offs[i] = o;
    cursor[i] = o;
}

// ---------------- K6: bucket packed (src<<6)|ty by dst ----------------
__global__ __launch_bounds__(256) void k_fill(const int* __restrict__ ei,
                                              const int* __restrict__ et,
                                              int* __restrict__ cursor,
                                              int* __restrict__ packed, int E) {
    int e = blockIdx.x * 256 + threadIdx.x;
    if (e >= E) return;
    int dn = ei[E + e];
    int p = (ei[e] << 6) | et[e];
    int pos = atomicAdd(&cursor[dn], 1);
    packed[pos] = p;
}

// ---------------- K7: gather per destination node, chunked via LDS ----------------
__global__ __launch_bounds__(128) void k_out(const int* __restrict__ packed,
                                             const int* __restrict__ offs,
                                             const float4* __restrict__ s1,
                                             const float4* __restrict__ s2,
                                             const float4* __restrict__ s3,
                                             const float* __restrict__ ab,
                                             const float* __restrict__ h,
                                             float* __restrict__ out) {
    __shared__ int src_l[128];
    __shared__ float es_l[128 * 4];
    int n = blockIdx.x;
    int d = threadIdx.x;  // 0..127
    int t = d;
    int hh = d >> 5;
    float b = ab[0];
    float4 s3n = s3[n];
    int beg = offs[n], end = offs[n + 1];
    int cnt = end - beg;
    float acc = 0.f, sum = 0.f;
    for (int base = 0; base < cnt; base += 128) {
        int m = cnt - base;
        if (m > 128) m = 128;
        __syncthreads();
        if (t < m) {
            int p = packed[beg + base + t];
            int s = p >> 6, ty = p & 63;
            float4 a = s1[s], c = s2[ty];
            float4 sc;
            sc.x = a.x + c.x + s3n.x + b;
            sc.y = a.y + c.y + s3n.y + b;
            sc.z = a.z + c.z + s3n.z + b;
            sc.w = a.w + c.w + s3n.w + b;
            sc.x = sc.x > 0.f ? sc.x : 0.2f * sc.x;
            sc.y = sc.y > 0.f ? sc.y : 0.2f * sc.y;
            sc.z = sc.z > 0.f ? sc.z : 0.2f * sc.z;
            sc.w = sc.w > 0.f ? sc.w : 0.2f * sc.w;
            src_l[t] = s;
            es_l[t * 4 + 0] = __expf(sc.x);
            es_l[t * 4 + 1] = __expf(sc.y);
            es_l[t * 4 + 2] = __expf(sc.z);
            es_l[t * 4 + 3] = __expf(sc.w);
        }
        __syncthreads();
        int i = 0;
        for (; i + 4 <= m; i += 4) {
            int a0 = src_l[i], a1 = src_l[i + 1], a2 = src_l[i + 2], a3 = src_l[i + 3];
            float e0 = es_l[i * 4 + hh], e1 = es_l[(i + 1) * 4 + hh];
            float e2 = es_l[(i + 2) * 4 + hh], e3 = es_l[(i + 3) * 4 + hh];
            float f0 = h[(size_t)a0 * DIM + d];
            float f1 = h[(size_t)a1 * DIM + d];
            float f2 = h[(size_t)a2 * DIM + d];
            float f3 = h[(size_t)a3 * DIM + d];
            sum += (e0 + e1) + (e2 + e3);
            acc += e0 * f0;
            acc += e1 * f1;
            acc += e2 * f2;
            acc += e3 * f3;
        }
        for (; i < m; ++i) {
            int s = src_l[i];
            float e = es_l[i * 4 + hh];
            sum += e;
            acc += e * h[(size_t)s * DIM + d];
        }
    }
    out[(size_t)n * DIM + d] = acc / (sum + 1e-8f);
}

extern "C" void kernel_launch(void* const* d_in, const int* in_sizes, int n_in,
                              void* d_out, int out_size, void* d_ws, size_t ws_size,
                              hipStream_t stream) {
    const float* ent = (const float*)d_in[0];
    const float* rel = (const float*)d_in[1];
    const int* ei = (const int*)d_in[2];   // [2,E]: src then dst
    const int* et = (const int*)d_in[3];   // [E]
    const float* W = (const float*)d_in[4];
    const float* Wr = (const float*)d_in[5];
    const float* aw = (const float*)d_in[6];
    const float* ab = (const float*)d_in[7];

    int N = in_sizes[0] / DIM;
    int R = in_sizes[1] / DIM;
    int E = in_sizes[3];
    int nb = (N + 255) / 256;

    // workspace layout (16B-aligned chunks)
    char* w = (char*)d_ws;
    float* h = (float*)w;      w += (size_t)N * DIM * 4;
    float* s1 = (float*)w;     w += (size_t)N * HEADS * 4;
    float* s3 = (float*)w;     w += (size_t)N * HEADS * 4;
    float* s2 = (float*)w;     w += ((size_t)R * HEADS * 4 + 15) / 16 * 16;
    float* v = (float*)w;      w += (size_t)DIM * HEADS * 4;
    int* deg = (int*)w;        w += (size_t)N * 4 + 16;
    int* offs = (int*)w;       w += ((size_t)(N + 1) * 4 + 15) / 16 * 16;
    int* cursor = (int*)w;     w += (size_t)N * 4;
    int* bsum = (int*)w;       w += ((size_t)nb * 4 + 15) / 16 * 16;
    int* packed = (int*)w;

    float* out = (float*)d_out;

    (void)hipMemsetAsync(deg, 0, (size_t)N * 4, stream);

    k_proj<<<(N + 63) / 64, 256, 0, stream>>>(ent, W, h, N);
    k_s13<<<(N * HEADS + 255) / 256, 256, 0, stream>>>(h, aw, s1, s3, N);
    k_v<<<(DIM * HEADS + 255) / 256, 256, 0, stream>>>(Wr, aw, v);
    k_s2<<<(R * HEADS + 3) / 4, 256, 0, stream>>>(rel, v, s2, R * HEADS);
    k_deg<<<(E + 255) / 256, 256, 0, stream>>>(ei, deg, E);
    k_scanA<<<nb, 256, 0, stream>>>(deg, offs, bsum, N);
    k_scanB<<<1, 1024, 0, stream>>>(bsum, offs, N, nb);
    k_scanC<<<nb, 256, 0, stream>>>(bsum, offs, cursor, N);
    k_fill<<<(E + 255) / 256, 256, 0, stream>>>(ei, et, cursor, packed, E);
    k_out<<<N, 128, 0, stream>>>(packed, offs, (const float4*)s1, (const float4*)s2,
                                 (const float4*)s3, ab, h, out);
}

// Round 7
// 239.763 us; speedup vs baseline: 2.7973x; 1.0338x over previous
//
#include <hip/hip_runtime.h>
#include <math.h>

#define HEADS 4
#define HD 32
#define DIM 128

__device__ __forceinline__ unsigned short f2bf(float x) {
    unsigned u = __float_as_uint(x);
    unsigned r = (u + 0x7FFFu + ((u >> 16) & 1u)) >> 16;  // RNE
    return (unsigned short)r;
}
__device__ __forceinline__ float bf2f(unsigned short v) {
    return __uint_as_float(((unsigned)v) << 16);
}

// ---- K1: h_bf16 = bf16(ent @ W^T); s1/s3 from acc registers; deg count fused ----
__global__ __launch_bounds__(256) void k_proj(const float* __restrict__ ent,
                                              const float* __restrict__ W,
                                              const float* __restrict__ aw,
                                              const int* __restrict__ ei,
                                              unsigned short* __restrict__ h16,
                                              float* __restrict__ s1,
                                              float* __restrict__ s3,
                                              int* __restrict__ deg,
                                              int N, int E) {
    __shared__ float4 eT[64 * 32];    // 64 rows x 128 floats (32 KB)
    __shared__ float4 wT[128 * 9];    // 128 cols x 8 float4 (+1 pad)
    int t = threadIdx.x;
    int row0 = blockIdx.x * 64;
    const float4* ent4 = (const float4*)ent;
    const float4* W4 = (const float4*)W;
    for (int i = t; i < 64 * 32; i += 256) {
        int r = row0 + (i >> 5);
        eT[i] = (r < N) ? ent4[(size_t)r * 32 + (i & 31)] : make_float4(0.f, 0.f, 0.f, 0.f);
    }
    // fused degree count: this block's slice of edges (atomics overlap GEMM)
    {
        int per = (E + gridDim.x - 1) / gridDim.x;
        int e0 = blockIdx.x * per;
        int e1 = e0 + per;
        if (e1 > E) e1 = E;
        for (int e = e0 + t; e < e1; e += 256) atomicAdd(&deg[ei[E + e]], 1);
    }
    int cx = t & 31;
    int ry = t >> 5;
    float acc[8][4] = {};
    for (int kc = 0; kc < 4; ++kc) {
        __syncthreads();  // also covers eT staging at kc=0
        for (int i = t; i < 128 * 8; i += 256) {
            int col = i >> 3, j = i & 7;
            wT[col * 9 + j] = W4[col * 32 + kc * 8 + j];
        }
        __syncthreads();
#pragma unroll
        for (int j = 0; j < 8; ++j) {
            float4 a[8], b[4];
#pragma unroll
            for (int r = 0; r < 8; ++r) a[r] = eT[(ry * 8 + r) * 32 + kc * 8 + j];
#pragma unroll
            for (int c = 0; c < 4; ++c) b[c] = wT[(cx + 32 * c) * 9 + j];
#pragma unroll
            for (int r = 0; r < 8; ++r)
#pragma unroll
                for (int c = 0; c < 4; ++c)
                    acc[r][c] += a[r].x * b[c].x + a[r].y * b[c].y +
                                 a[r].z * b[c].z + a[r].w * b[c].w;
        }
    }
    // epilogue: bf16 h store + s1/s3 via 32-lane shuffle reduction
    float w1 = aw[cx];        // aw[0:32] (same for every head)
    float w3 = aw[64 + cx];   // aw[64:96]
    for (int r = 0; r < 8; ++r) {
        int gr = row0 + ry * 8 + r;
        if (gr < N) {
#pragma unroll
            for (int c = 0; c < 4; ++c)
                h16[(size_t)gr * DIM + cx + 32 * c] = f2bf(acc[r][c]);
        }
#pragma unroll
        for (int c = 0; c < 4; ++c) {   // head index == c
            float v1 = acc[r][c] * w1;
            float v3 = acc[r][c] * w3;
#pragma unroll
            for (int off = 16; off > 0; off >>= 1) {
                v1 += __shfl_down(v1, off);
                v3 += __shfl_down(v3, off);
            }
            if ((t & 31) == 0 && gr < N) {
                s1[gr * 4 + c] = v1;
                s3[gr * 4 + c] = v3;
            }
        }
    }
}

// ---- K2: s2[rel,hh]; v recomputed per block in LDS (Wr stays L2-hot) ----
__global__ __launch_bounds__(256) void k_s2(const float* __restrict__ rel,
                                            const float* __restrict__ Wr,
                                            const float* __restrict__ aw,
                                            float* __restrict__ s2, int RH) {
    __shared__ float v[DIM * HEADS];
    int t = threadIdx.x;
    for (int i = t; i < DIM * HEADS; i += 256) {
        int k = i >> 2, hh = i & 3;
        float a = 0.f;
        for (int j = 0; j < 32; ++j) a += Wr[(hh * 32 + j) * DIM + k] * aw[32 + j];
        v[i] = a;  // i == k*4+hh
    }
    __syncthreads();
    int o = blockIdx.x * 4 + (t >> 6);
    if (o >= RH) return;
    int r = o >> 2, hh = o & 3;
    int l = t & 63;
    float p = rel[r * DIM + l] * v[l * 4 + hh] + rel[r * DIM + 64 + l] * v[(64 + l) * 4 + hh];
#pragma unroll
    for (int off = 32; off > 0; off >>= 1) p += __shfl_down(p, off);
    if (l == 0) s2[o] = p;
}

// ---- K3a: per-block scan of deg ----
__global__ __launch_bounds__(256) void k_scanA(const int* __restrict__ deg,
                                               int* __restrict__ offs,
                                               int* __restrict__ bsum, int N) {
    __shared__ int sm[256];
    int t = threadIdx.x;
    int i = blockIdx.x * 256 + t;
    int v = (i < N) ? deg[i] : 0;
    sm[t] = v;
    __syncthreads();
    for (int off = 1; off < 256; off <<= 1) {
        int x = (t >= off) ? sm[t - off] : 0;
        __syncthreads();
        sm[t] += x;
        __syncthreads();
    }
    if (i < N) offs[i] = sm[t] - v;
    if (t == 255) bsum[blockIdx.x] = sm[255];
}

// ---- K3b: exclusive scan of bsum (nb ~157) ----
__global__ __launch_bounds__(1024) void k_scanB(int* __restrict__ bsum,
                                                int* __restrict__ offs,
                                                int N, int nb) {
    __shared__ int partial[1024];
    int t = threadIdx.x;
    int per = (nb + 1023) / 1024;
    int start = t * per;
    int end = start + per;
    if (end > nb) end = nb;
    int sum = 0;
    for (int i = start; i < end; ++i) sum += bsum[i];
    partial[t] = sum;
    __syncthreads();
    for (int off = 1; off < 1024; off <<= 1) {
        int x = (t >= off) ? partial[t - off] : 0;
        __syncthreads();
        partial[t] += x;
        __syncthreads();
    }
    int run = (t > 0) ? partial[t - 1] : 0;
    for (int i = start; i < end; ++i) {
        int v = bsum[i];
        bsum[i] = run;
        run += v;
    }
    if (t == 1023) offs[N] = partial[1023];
}

// ---- K3c: add block prefix; mirror into cursor ----
__global__ __launch_bounds__(256) void k_scanC(const int* __restrict__ bsum,
                                               int* __restrict__ offs,
                                               int* __restrict__ cursor, int N) {
    int i = blockIdx.x * 256 + threadIdx.x;
    if (i >= N) return;
    int o = offs[i] + bsum[blockIdx.x];
    offs[i] = o;
    cursor[i] = o;
}

// ---- K4: bucket packed (src<<6)|ty by dst ----
__global__ __launch_bounds__(256) void k_fill(const int* __restrict__ ei,
                                              const int* __restrict__ et,
                                              int* __restrict__ cursor,
                                              int* __restrict__ packed, int E) {
    int e = blockIdx.x * 256 + threadIdx.x;
    if (e >= E) return;
    int dn = ei[E + e];
    int p = (ei[e] << 6) | et[e];
    int pos = atomicAdd(&cursor[dn], 1);
    packed[pos] = p;
}

// ---- K5: gather per destination node, bf16 h ----
__global__ __launch_bounds__(128) void k_out(const int* __restrict__ packed,
                                             const int* __restrict__ offs,
                                             const float4* __restrict__ s1,
                                             const float4* __restrict__ s2,
                                             const float4* __restrict__ s3,
                                             const float* __restrict__ ab,
                                             const unsigned short* __restrict__ h16,
                                             float* __restrict__ out) {
    __shared__ int src_l[128];
    __shared__ float es_l[128 * 4];
    int n = blockIdx.x;
    int d = threadIdx.x;  // 0..127
    int t = d;
    int hh = d >> 5;
    float b = ab[0];
    float4 s3n = s3[n];
    int beg = offs[n], end = offs[n + 1];
    int cnt = end - beg;
    float acc = 0.f, sum = 0.f;
    for (int base = 0; base < cnt; base += 128) {
        int m = cnt - base;
        if (m > 128) m = 128;
        __syncthreads();
        if (t < m) {
            int p = packed[beg + base + t];
            int s = p >> 6, ty = p & 63;
            float4 a = s1[s], c = s2[ty];
            float4 sc;
            sc.x = a.x + c.x + s3n.x + b;
            sc.y = a.y + c.y + s3n.y + b;
            sc.z = a.z + c.z + s3n.z + b;
            sc.w = a.w + c.w + s3n.w + b;
            sc.x = sc.x > 0.f ? sc.x : 0.2f * sc.x;
            sc.y = sc.y > 0.f ? sc.y : 0.2f * sc.y;
            sc.z = sc.z > 0.f ? sc.z : 0.2f * sc.z;
            sc.w = sc.w > 0.f ? sc.w : 0.2f * sc.w;
            src_l[t] = s;
            es_l[t * 4 + 0] = __expf(sc.x);
            es_l[t * 4 + 1] = __expf(sc.y);
            es_l[t * 4 + 2] = __expf(sc.z);
            es_l[t * 4 + 3] = __expf(sc.w);
        }
        __syncthreads();
        int i = 0;
        for (; i + 4 <= m; i += 4) {
            int a0 = src_l[i], a1 = src_l[i + 1], a2 = src_l[i + 2], a3 = src_l[i + 3];
            float e0 = es_l[i * 4 + hh], e1 = es_l[(i + 1) * 4 + hh];
            float e2 = es_l[(i + 2) * 4 + hh], e3 = es_l[(i + 3) * 4 + hh];
            float f0 = bf2f(h16[(size_t)a0 * DIM + d]);
            float f1 = bf2f(h16[(size_t)a1 * DIM + d]);
            float f2 = bf2f(h16[(size_t)a2 * DIM + d]);
            float f3 = bf2f(h16[(size_t)a3 * DIM + d]);
            sum += (e0 + e1) + (e2 + e3);
            acc += e0 * f0;
            acc += e1 * f1;
            acc += e2 * f2;
            acc += e3 * f3;
        }
        for (; i < m; ++i) {
            int s = src_l[i];
            float e = es_l[i * 4 + hh];
            sum += e;
            acc += e * bf2f(h16[(size_t)s * DIM + d]);
        }
    }
    out[(size_t)n * DIM + d] = acc / (sum + 1e-8f);
}

extern "C" void kernel_launch(void* const* d_in, const int* in_sizes, int n_in,
                              void* d_out, int out_size, void* d_ws, size_t ws_size,
                              hipStream_t stream) {
    const float* ent = (const float*)d_in[0];
    const float* rel = (const float*)d_in[1];
    const int* ei = (const int*)d_in[2];   // [2,E]: src then dst
    const int* et = (const int*)d_in[3];   // [E]
    const float* W = (const float*)d_in[4];
    const float* Wr = (const float*)d_in[5];
    const float* aw = (const float*)d_in[6];
    const float* ab = (const float*)d_in[7];

    int N = in_sizes[0] / DIM;
    int R = in_sizes[1] / DIM;
    int E = in_sizes[3];
    int nb = (N + 255) / 256;

    // workspace layout (16B-aligned chunks)
    char* w = (char*)d_ws;
    unsigned short* h16 = (unsigned short*)w; w += ((size_t)N * DIM * 2 + 15) / 16 * 16;
    float* s1 = (float*)w;     w += (size_t)N * HEADS * 4;
    float* s3 = (float*)w;     w += (size_t)N * HEADS * 4;
    float* s2 = (float*)w;     w += ((size_t)R * HEADS * 4 + 15) / 16 * 16;
    int* deg = (int*)w;        w += (size_t)N * 4 + 16;
    int* offs = (int*)w;       w += ((size_t)(N + 1) * 4 + 15) / 16 * 16;
    int* cursor = (int*)w;     w += (size_t)N * 4;
    int* bsum = (int*)w;       w += ((size_t)nb * 4 + 15) / 16 * 16;
    int* packed = (int*)w;

    float* out = (float*)d_out;

    (void)hipMemsetAsync(deg, 0, (size_t)N * 4, stream);

    k_proj<<<(N + 63) / 64, 256, 0, stream>>>(ent, W, aw, ei, h16, s1, s3, deg, N, E);
    k_s2<<<(R * HEADS + 3) / 4, 256, 0, stream>>>(rel, Wr, aw, s2, R * HEADS);
    k_scanA<<<nb, 256, 0, stream>>>(deg, offs, bsum, N);
    k_scanB<<<1, 1024, 0, stream>>>(bsum, offs, N, nb);
    k_scanC<<<nb, 256, 0, stream>>>(bsum, offs, cursor, N);
    k_fill<<<(E + 255) / 256, 256, 0, stream>>>(ei, et, cursor, packed, E);
    k_out<<<N, 128, 0, stream>>>(packed, offs, (const float4*)s1, (const float4*)s2,
                                 (const float4*)s3, ab, h16, out);
}

// Round 8
// 188.648 us; speedup vs baseline: 3.5553x; 1.2710x over previous
//
#include <hip/hip_runtime.h>
#include <math.h>

#define HEADS 4
#define DIM 128
#define LSTRIDE 136  // 128 + 8 bf16 pad: row stride 272 B -> conflict-free b128 frag reads

typedef __bf16 bf16x8 __attribute__((ext_vector_type(8)));
typedef float f32x4 __attribute__((ext_vector_type(4)));

__device__ __forceinline__ unsigned short f2bf(float x) {
    unsigned u = __float_as_uint(x);
    unsigned r = (u + 0x7FFFu + ((u >> 16) & 1u)) >> 16;  // RNE
    return (unsigned short)r;
}
__device__ __forceinline__ float bf2f(unsigned short v) {
    return __uint_as_float(((unsigned)v) << 16);
}

// ---- K1: h16 = bf16(ent @ W^T) via MFMA; s1/s3 from fp32 acc; deg fused ----
// Block: 64 entity rows x 128 dims, 4 waves; wave handles 16 rows.
// MFMA 16x16x32_bf16: A=W (m=dim), B=ent (n=entity row). K=128 -> 4 k-steps.
__global__ __launch_bounds__(256) void k_proj(const float* __restrict__ ent,
                                              const float* __restrict__ W,
                                              const float* __restrict__ aw,
                                              const int* __restrict__ ei,
                                              unsigned short* __restrict__ h16,
                                              float4* __restrict__ s1,
                                              float4* __restrict__ s3,
                                              int* __restrict__ deg,
                                              int N, int E) {
    __shared__ unsigned short eL[64 * LSTRIDE];    // 17.4 KB
    __shared__ unsigned short wL[128 * LSTRIDE];   // 34.8 KB
    int t = threadIdx.x;
    int row0 = blockIdx.x * 64;
    const float4* ent4 = (const float4*)ent;
    const float4* W4 = (const float4*)W;
    // stage ent tile as bf16
    for (int i = t; i < 64 * 32; i += 256) {
        int r = i >> 5, k4 = i & 31;
        int gr = row0 + r;
        float4 v = (gr < N) ? ent4[(size_t)gr * 32 + k4] : make_float4(0.f, 0.f, 0.f, 0.f);
        unsigned short* p = &eL[r * LSTRIDE + k4 * 4];
        p[0] = f2bf(v.x); p[1] = f2bf(v.y); p[2] = f2bf(v.z); p[3] = f2bf(v.w);
    }
    // stage W as bf16
    for (int i = t; i < 128 * 32; i += 256) {
        int r = i >> 5, k4 = i & 31;
        float4 v = W4[r * 32 + k4];
        unsigned short* p = &wL[r * LSTRIDE + k4 * 4];
        p[0] = f2bf(v.x); p[1] = f2bf(v.y); p[2] = f2bf(v.z); p[3] = f2bf(v.w);
    }
    // fused degree count (overlaps staging/MFMA; different pipes)
    {
        int per = (E + gridDim.x - 1) / gridDim.x;
        int e0 = blockIdx.x * per;
        int e1 = e0 + per;
        if (e1 > E) e1 = E;
        for (int e = e0 + t; e < e1; e += 256) atomicAdd(&deg[ei[E + e]], 1);
    }
    __syncthreads();
    int wv = t >> 6, lane = t & 63, ln = lane & 15, quad = lane >> 4;
    int er = wv * 16 + ln;  // entity row in tile (B-operand n = lane&15)
    bf16x8 bfr[4];
#pragma unroll
    for (int ks = 0; ks < 4; ++ks)
        bfr[ks] = *(const bf16x8*)&eL[er * LSTRIDE + ks * 32 + quad * 8];
    f32x4 acc[8];
#pragma unroll
    for (int mt = 0; mt < 8; ++mt) acc[mt] = (f32x4){0.f, 0.f, 0.f, 0.f};
#pragma unroll
    for (int ks = 0; ks < 4; ++ks) {
#pragma unroll
        for (int mt = 0; mt < 8; ++mt) {
            bf16x8 afr = *(const bf16x8*)&wL[(mt * 16 + ln) * LSTRIDE + ks * 32 + quad * 8];
            acc[mt] = __builtin_amdgcn_mfma_f32_16x16x32_bf16(afr, bfr[ks], acc[mt], 0, 0, 0);
        }
    }
    // D layout: col(entity row)=lane&15, row(dim)=mt*16+quad*4+reg -> 4 contiguous dims
    int gr = row0 + er;
    const float4* awv = (const float4*)aw;
    float s1h[4] = {0.f, 0.f, 0.f, 0.f}, s3h[4] = {0.f, 0.f, 0.f, 0.f};
#pragma unroll
    for (int mt = 0; mt < 8; ++mt) {
        int d0 = mt * 16 + quad * 4;
        if (gr < N) {
            ushort4 us;
            us.x = f2bf(acc[mt][0]); us.y = f2bf(acc[mt][1]);
            us.z = f2bf(acc[mt][2]); us.w = f2bf(acc[mt][3]);
            *(ushort4*)&h16[(size_t)gr * DIM + d0] = us;
        }
        int wi = (mt & 1) * 4 + quad;  // weight index = (d0 % 32)/4, same aw per head
        float4 w1 = awv[wi], w3 = awv[16 + wi];
        int hh = mt >> 1;
        s1h[hh] += acc[mt][0] * w1.x + acc[mt][1] * w1.y + acc[mt][2] * w1.z + acc[mt][3] * w1.w;
        s3h[hh] += acc[mt][0] * w3.x + acc[mt][1] * w3.y + acc[mt][2] * w3.z + acc[mt][3] * w3.w;
    }
#pragma unroll
    for (int hh = 0; hh < HEADS; ++hh) {
        s1h[hh] += __shfl_xor(s1h[hh], 16);
        s1h[hh] += __shfl_xor(s1h[hh], 32);
        s3h[hh] += __shfl_xor(s3h[hh], 16);
        s3h[hh] += __shfl_xor(s3h[hh], 32);
    }
    if (quad == 0 && gr < N) {
        s1[gr] = make_float4(s1h[0], s1h[1], s1h[2], s1h[3]);
        s3[gr] = make_float4(s3h[0], s3h[1], s3h[2], s3h[3]);
    }
}

// ---- K2: s2[rel,hh]; v recomputed per block in LDS ----
__global__ __launch_bounds__(256) void k_s2(const float* __restrict__ rel,
                                            const float* __restrict__ Wr,
                                            const float* __restrict__ aw,
                                            float* __restrict__ s2, int RH) {
    __shared__ float v[DIM * HEADS];
    int t = threadIdx.x;
    for (int i = t; i < DIM * HEADS; i += 256) {
        int k = i >> 2, hh = i & 3;
        float a = 0.f;
        for (int j = 0; j < 32; ++j) a += Wr[(hh * 32 + j) * DIM + k] * aw[32 + j];
        v[i] = a;  // i == k*4+hh
    }
    __syncthreads();
    int o = blockIdx.x * 4 + (t >> 6);
    if (o >= RH) return;
    int r = o >> 2, hh = o & 3;
    int l = t & 63;
    float p = rel[r * DIM + l] * v[l * 4 + hh] + rel[r * DIM + 64 + l] * v[(64 + l) * 4 + hh];
#pragma unroll
    for (int off = 32; off > 0; off >>= 1) p += __shfl_down(p, off);
    if (l == 0) s2[o] = p;
}

// ---- K3a: per-block scan of deg -> local exclusive offs + block totals ----
__global__ __launch_bounds__(256) void k_scanA(const int* __restrict__ deg,
                                               int* __restrict__ offs,
                                               int* __restrict__ bsum, int N) {
    __shared__ int sm[256];
    int t = threadIdx.x;
    int i = blockIdx.x * 256 + t;
    int v = (i < N) ? deg[i] : 0;
    sm[t] = v;
    __syncthreads();
    for (int off = 1; off < 256; off <<= 1) {
        int x = (t >= off) ? sm[t - off] : 0;
        __syncthreads();
        sm[t] += x;
        __syncthreads();
    }
    if (i < N) offs[i] = sm[t] - v;
    if (t == 255) bsum[blockIdx.x] = sm[255];
}

// ---- K3b: exclusive scan of bsum in place (nb ~157) ----
__global__ __launch_bounds__(1024) void k_scanB(int* __restrict__ bsum, int nb) {
    __shared__ int partial[1024];
    int t = threadIdx.x;
    int per = (nb + 1023) / 1024;
    int start = t * per;
    int end = start + per;
    if (end > nb) end = nb;
    int sum = 0;
    for (int i = start; i < end; ++i) sum += bsum[i];
    partial[t] = sum;
    __syncthreads();
    for (int off = 1; off < 1024; off <<= 1) {
        int x = (t >= off) ? partial[t - off] : 0;
        __syncthreads();
        partial[t] += x;
        __syncthreads();
    }
    int run = (t > 0) ? partial[t - 1] : 0;
    for (int i = start; i < end; ++i) {
        int v = bsum[i];
        bsum[i] = run;
        run += v;
    }
}

// ---- K4: bucket packed (src<<6)|ty by dst; prefix folded, zero-based cnt ----
__global__ __launch_bounds__(256) void k_fill(const int* __restrict__ ei,
                                              const int* __restrict__ et,
                                              const int* __restrict__ offs,
                                              const int* __restrict__ bsum,
                                              int* __restrict__ cnt,
                                              int* __restrict__ packed, int E) {
    int e = blockIdx.x * 256 + threadIdx.x;
    if (e >= E) return;
    int dn = ei[E + e];
    int pos = offs[dn] + bsum[dn >> 8] + atomicAdd(&cnt[dn], 1);
    packed[pos] = (ei[e] << 6) | et[e];
}

// ---- K5: gather per destination node; uint (2x bf16) loads, 64 threads ----
__global__ __launch_bounds__(64) void k_out(const int* __restrict__ packed,
                                            const int* __restrict__ offs,
                                            const int* __restrict__ bsum,
                                            const float4* __restrict__ s1,
                                            const float4* __restrict__ s2,
                                            const float4* __restrict__ s3,
                                            const float* __restrict__ ab,
                                            const unsigned short* __restrict__ h16,
                                            float* __restrict__ out, int N, int E) {
    __shared__ int src_l[64];
    __shared__ float es_l[64 * 4];
    int n = blockIdx.x;
    int t = threadIdx.x;  // 0..63, handles dims 2t, 2t+1
    int hh = t >> 4;
    float b = ab[0];
    float4 s3n = s3[n];
    int beg = offs[n] + bsum[n >> 8];
    int end = (n + 1 < N) ? (offs[n + 1] + bsum[(n + 1) >> 8]) : E;
    int cnt = end - beg;
    float a0 = 0.f, a1 = 0.f, sum = 0.f;
    for (int base = 0; base < cnt; base += 64) {
        int m = cnt - base;
        if (m > 64) m = 64;
        __syncthreads();
        if (t < m) {
            int p = packed[beg + base + t];
            int s = p >> 6, ty = p & 63;
            float4 a = s1[s], c = s2[ty];
            float4 sc;
            sc.x = a.x + c.x + s3n.x + b;
            sc.y = a.y + c.y + s3n.y + b;
            sc.z = a.z + c.z + s3n.z + b;
            sc.w = a.w + c.w + s3n.w + b;
            sc.x = sc.x > 0.f ? sc.x : 0.2f * sc.x;
            sc.y = sc.y > 0.f ? sc.y : 0.2f * sc.y;
            sc.z = sc.z > 0.f ? sc.z : 0.2f * sc.z;
            sc.w = sc.w > 0.f ? sc.w : 0.2f * sc.w;
            src_l[t] = s;
            es_l[t * 4 + 0] = __expf(sc.x);
            es_l[t * 4 + 1] = __expf(sc.y);
            es_l[t * 4 + 2] = __expf(sc.z);
            es_l[t * 4 + 3] = __expf(sc.w);
        }
        __syncthreads();
        int i = 0;
        for (; i + 4 <= m; i += 4) {
            int q0 = src_l[i], q1 = src_l[i + 1], q2 = src_l[i + 2], q3 = src_l[i + 3];
            float e0 = es_l[i * 4 + hh], e1 = es_l[(i + 1) * 4 + hh];
            float e2 = es_l[(i + 2) * 4 + hh], e3 = es_l[(i + 3) * 4 + hh];
            unsigned v0 = *(const unsigned*)&h16[(size_t)q0 * DIM + 2 * t];
            unsigned v1 = *(const unsigned*)&h16[(size_t)q1 * DIM + 2 * t];
            unsigned v2 = *(const unsigned*)&h16[(size_t)q2 * DIM + 2 * t];
            unsigned v3 = *(const unsigned*)&h16[(size_t)q3 * DIM + 2 * t];
            sum += (e0 + e1) + (e2 + e3);
            a0 += e0 * bf2f((unsigned short)v0);
            a1 += e0 * bf2f((unsigned short)(v0 >> 16));
            a0 += e1 * bf2f((unsigned short)v1);
            a1 += e1 * bf2f((unsigned short)(v1 >> 16));
            a0 += e2 * bf2f((unsigned short)v2);
            a1 += e2 * bf2f((unsigned short)(v2 >> 16));
            a0 += e3 * bf2f((unsigned short)v3);
            a1 += e3 * bf2f((unsigned short)(v3 >> 16));
        }
        for (; i < m; ++i) {
            int s = src_l[i];
            float e = es_l[i * 4 + hh];
            unsigned v = *(const unsigned*)&h16[(size_t)s * DIM + 2 * t];
            sum += e;
            a0 += e * bf2f((unsigned short)v);
            a1 += e * bf2f((unsigned short)(v >> 16));
        }
    }
    float inv = 1.f / (sum + 1e-8f);
    *(float2*)&out[(size_t)n * DIM + 2 * t] = make_float2(a0 * inv, a1 * inv);
}

extern "C" void kernel_launch(void* const* d_in, const int* in_sizes, int n_in,
                              void* d_out, int out_size, void* d_ws, size_t ws_size,
                              hipStream_t stream) {
    const float* ent = (const float*)d_in[0];
    const float* rel = (const float*)d_in[1];
    const int* ei = (const int*)d_in[2];   // [2,E]: src then dst
    const int* et = (const int*)d_in[3];   // [E]
    const float* W = (const float*)d_in[4];
    const float* Wr = (const float*)d_in[5];
    const float* aw = (const float*)d_in[6];
    const float* ab = (const float*)d_in[7];

    int N = in_sizes[0] / DIM;
    int R = in_sizes[1] / DIM;
    int E = in_sizes[3];
    int nb = (N + 255) / 256;

    // workspace layout (16B-aligned chunks)
    char* w = (char*)d_ws;
    unsigned short* h16 = (unsigned short*)w; w += ((size_t)N * DIM * 2 + 15) / 16 * 16;
    float* s1 = (float*)w;     w += (size_t)N * HEADS * 4;
    float* s3 = (float*)w;     w += (size_t)N * HEADS * 4;
    float* s2 = (float*)w;     w += ((size_t)R * HEADS * 4 + 15) / 16 * 16;
    int* deg = (int*)w;        w += (size_t)N * 4;
    int* cnt = (int*)w;        w += (size_t)N * 4;   // contiguous with deg: one memset
    int* offs = (int*)w;       w += ((size_t)N * 4 + 15) / 16 * 16;
    int* bsum = (int*)w;       w += ((size_t)nb * 4 + 15) / 16 * 16;
    int* packed = (int*)w;

    float* out = (float*)d_out;

    (void)hipMemsetAsync(deg, 0, (size_t)N * 8, stream);  // deg + cnt

    k_proj<<<(N + 63) / 64, 256, 0, stream>>>(ent, W, aw, ei, h16, (float4*)s1,
                                              (float4*)s3, deg, N, E);
    k_s2<<<(R * HEADS + 3) / 4, 256, 0, stream>>>(rel, Wr, aw, s2, R * HEADS);
    k_scanA<<<nb, 256, 0, stream>>>(deg, offs, bsum, N);
    k_scanB<<<1, 1024, 0, stream>>>(bsum, nb);
    k_fill<<<(E + 255) / 256, 256, 0, stream>>>(ei, et, offs, bsum, cnt, packed, E);
    k_out<<<N, 64, 0, stream>>>(packed, offs, bsum, (const float4*)s1, (const float4*)s2,
                                (const float4*)s3, ab, h16, out, N, E);
}